// Round 1
// baseline (386.900 us; speedup 1.0000x reference)
//
#include <hip/hip_runtime.h>
#include <hip/hip_bf16.h>

#define NTOT 1048576
#define NSEG 4096
#define HDIM 128
#define ODIM 256
#define BN   64

typedef __attribute__((ext_vector_type(8))) short bf16x8;
typedef __attribute__((ext_vector_type(4))) float f32x4;
typedef __attribute__((ext_vector_type(2))) unsigned int u32x2;
typedef __attribute__((ext_vector_type(4))) float float4v;

__device__ __forceinline__ unsigned short f32_to_bf16_rne(float f) {
    unsigned int u = __builtin_bit_cast(unsigned int, f);
    unsigned int r = (u + 0x7fffu + ((u >> 16) & 1u)) >> 16;
    return (unsigned short)r;
}

__global__ void convert_w1(const float* __restrict__ W1, unsigned short* __restrict__ W1b) {
    int i = blockIdx.x * 256 + threadIdx.x;
    W1b[i] = f32_to_bf16_rne(W1[i]);
}

// Fused: s = x@W1^T ; phi = tanh(s+b1) ; sumx[seg] += phi   (batch sorted)
__global__ __launch_bounds__(256, 2)
void stage1(const float* __restrict__ x, const int* __restrict__ batch,
            const unsigned short* __restrict__ W1b, const float* __restrict__ b1,
            float* __restrict__ sumx) {
    __shared__ __align__(16) unsigned char smem[BN * 257 * 4]; // A-tile (16KB, swizzled) then phi[64][257] f32
    __shared__ int seg[BN];

    const int t    = threadIdx.x;
    const int lane = t & 63;
    const int wv   = t >> 6;
    const int l15  = lane & 15;
    const int lhi  = lane >> 4;
    const long n0  = (long)blockIdx.x * BN;

    // dtype probe: int64 little-endian => odd words are high words == 0
    const bool is64 = (batch[NTOT - 1] == 0);
    if (t < BN) {
        long idx = n0 + t;
        seg[t] = batch[is64 ? 2 * idx : idx];
    }

    // stage x[64][128] f32 -> bf16 A in LDS, XOR-swizzled (G4: avoid 32-way conflict)
    #pragma unroll
    for (int i = 0; i < 8; ++i) {
        int idx = i * 256 + t;
        int row = idx >> 5;        // 32 float4 per row
        int c4  = idx & 31;
        const float4v xv = *(const float4v*)(x + (n0 + row) * HDIM + c4 * 4);
        unsigned int p0 = ((unsigned int)f32_to_bf16_rne(xv.y) << 16) | f32_to_bf16_rne(xv.x);
        unsigned int p1 = ((unsigned int)f32_to_bf16_rne(xv.w) << 16) | f32_to_bf16_rne(xv.z);
        int boff = row * 256 + ((c4 * 8) ^ ((row & 7) << 4));
        *(u32x2*)(smem + boff) = (u32x2){p0, p1};
    }
    __syncthreads();

    f32x4 acc[4][4];
    #pragma unroll
    for (int mf = 0; mf < 4; ++mf)
        #pragma unroll
        for (int nf = 0; nf < 4; ++nf)
            acc[mf][nf] = (f32x4){0.f, 0.f, 0.f, 0.f};

    // K = 128 in 4 steps of 32; wave wv owns output cols [wv*64, wv*64+64)
    #pragma unroll
    for (int ks = 0; ks < 4; ++ks) {
        const int k0 = ks * 32 + lhi * 8;
        bf16x8 bfrag[4];
        #pragma unroll
        for (int nf = 0; nf < 4; ++nf) {
            int n = wv * 64 + nf * 16 + l15;          // W1 row (output feature)
            bfrag[nf] = *(const bf16x8*)(W1b + n * HDIM + k0);
        }
        bf16x8 afrag[4];
        #pragma unroll
        for (int mf = 0; mf < 4; ++mf) {
            int m = mf * 16 + l15;
            int boff = m * 256 + (((k0) * 2) ^ ((m & 7) << 4));
            afrag[mf] = *(const bf16x8*)(smem + boff);
        }
        #pragma unroll
        for (int mf = 0; mf < 4; ++mf)
            #pragma unroll
            for (int nf = 0; nf < 4; ++nf)
                acc[mf][nf] = __builtin_amdgcn_mfma_f32_16x16x32_bf16(
                    afrag[mf], bfrag[nf], acc[mf][nf], 0, 0, 0);
    }

    // bias + fast tanh in registers: tanh(s) = 1 - 2/(1 + 2^(s*2*log2 e))
    float bias[4];
    #pragma unroll
    for (int nf = 0; nf < 4; ++nf) bias[nf] = b1[wv * 64 + nf * 16 + l15];
    #pragma unroll
    for (int mf = 0; mf < 4; ++mf)
        #pragma unroll
        for (int nf = 0; nf < 4; ++nf)
            #pragma unroll
            for (int r = 0; r < 4; ++r) {
                float s = acc[mf][nf][r] + bias[nf];
                float e = exp2f(s * 2.88539008177793f);
                acc[mf][nf][r] = 1.0f - 2.0f * __builtin_amdgcn_rcpf(1.0f + e);
            }

    __syncthreads();   // everyone done reading A-tile; reuse smem as phi
    float* phi = (float*)smem;
    #pragma unroll
    for (int mf = 0; mf < 4; ++mf)
        #pragma unroll
        for (int nf = 0; nf < 4; ++nf) {
            int col = wv * 64 + nf * 16 + l15;
            #pragma unroll
            for (int r = 0; r < 4; ++r) {
                int row = mf * 16 + lhi * 4 + r;      // verified C/D mapping (m89)
                phi[row * 257 + col] = acc[mf][nf][r];
            }
        }
    __syncthreads();

    // segmented column reduction: thread t owns col t, walks 64 sorted rows
    {
        const int col = t;
        float a = phi[col];
        int cur = seg[0];
        #pragma unroll 8
        for (int m = 1; m < BN; ++m) {
            float v = phi[m * 257 + col];
            int s = seg[m];
            if (s != cur) {                    // uniform branch (seg[] same for all lanes)
                atomicAdd(&sumx[(long)cur * ODIM + col], a);
                a = 0.0f;
                cur = s;
            }
            a += v;
        }
        atomicAdd(&sumx[(long)cur * ODIM + col], a);
    }
}

// y[g][h] = b2[h] + sum_o sumx[g][o] * W2[h][o]   (fp32, 268 MFLOP)
__global__ __launch_bounds__(256)
void stage2(const float* __restrict__ sumx, const float* __restrict__ W2,
            const float* __restrict__ b2, float* __restrict__ y) {
    __shared__ float sx[16 * 256];
    const int t = threadIdx.x;
    const long g0 = (long)blockIdx.x * 16;
    #pragma unroll
    for (int i = 0; i < 16; ++i)
        sx[i * 256 + t] = sumx[(g0 + i) * 256 + t];
    __syncthreads();
    const int h = t & 127;
    const int gl0 = (t >> 7) * 8;
    float acc[8] = {0, 0, 0, 0, 0, 0, 0, 0};
    const float* w = W2 + h * 256;
    for (int o4 = 0; o4 < 64; ++o4) {
        float4v wvv = *(const float4v*)(w + o4 * 4);
        #pragma unroll
        for (int gl = 0; gl < 8; ++gl) {
            const float* sr = &sx[(gl0 + gl) * 256 + o4 * 4];
            acc[gl] += sr[0] * wvv.x + sr[1] * wvv.y + sr[2] * wvv.z + sr[3] * wvv.w;
        }
    }
    float bb = b2[h];
    #pragma unroll
    for (int gl = 0; gl < 8; ++gl)
        y[(g0 + gl0 + gl) * 128 + h] = acc[gl] + bb;
}

extern "C" void kernel_launch(void* const* d_in, const int* in_sizes, int n_in,
                              void* d_out, int out_size, void* d_ws, size_t ws_size,
                              hipStream_t stream) {
    const float* x  = (const float*)d_in[0];
    const int* batch = (const int*)d_in[1];
    const float* W1 = (const float*)d_in[2];
    const float* b1 = (const float*)d_in[3];
    const float* W2 = (const float*)d_in[4];
    const float* b2 = (const float*)d_in[5];
    float* y = (float*)d_out;

    float* sumx = (float*)d_ws;                                            // 4 MB
    unsigned short* W1b = (unsigned short*)((char*)d_ws + (size_t)NSEG * ODIM * 4); // 64 KB

    hipMemsetAsync(sumx, 0, (size_t)NSEG * ODIM * sizeof(float), stream);
    convert_w1<<<dim3((ODIM * HDIM) / 256), dim3(256), 0, stream>>>(W1, W1b);
    stage1<<<dim3(NTOT / BN), dim3(256), 0, stream>>>(x, batch, W1b, b1, sumx);
    stage2<<<dim3(NSEG / 16), dim3(256), 0, stream>>>(sumx, W2, b2, y);
}

// Round 3
// 234.382 us; speedup vs baseline: 1.6507x; 1.6507x over previous
//
#include <hip/hip_runtime.h>
#include <hip/hip_bf16.h>

#define NTOT 1048576
#define NSEG 4096
#define HDIM 128
#define ODIM 256
#define BN   64

typedef __attribute__((ext_vector_type(8))) short bf16x8;
typedef __attribute__((ext_vector_type(4))) float f32x4;
typedef __attribute__((ext_vector_type(2))) unsigned int u32x2;

__device__ __forceinline__ unsigned short f32_to_bf16_rne(float f) {
    unsigned int u = __builtin_bit_cast(unsigned int, f);
    unsigned int r = (u + 0x7fffu + ((u >> 16) & 1u)) >> 16;
    return (unsigned short)r;
}
__device__ __forceinline__ unsigned int pk_bf16(float lo, float hi) {
    return ((unsigned int)f32_to_bf16_rne(hi) << 16) | f32_to_bf16_rne(lo);
}

__global__ void convert_w1(const float* __restrict__ W1, unsigned int* __restrict__ W1b) {
    int i = blockIdx.x * 256 + threadIdx.x;          // one packed u32 (2 bf16) per thread
    float2 v = *(const float2*)(W1 + 2 * i);
    W1b[i] = pk_bf16(v.x, v.y);
}

// Fused: s = x@W1^T + b1 (MFMA, bias in C-init); phi = tanh(s);
// segment-sum entirely in registers (batch sorted) -> atomicAdd per run.
__global__ __launch_bounds__(256, 4)
void stage1(const float* __restrict__ x, const int* __restrict__ batch,
            const unsigned short* __restrict__ W1b, const float* __restrict__ b1,
            float* __restrict__ sumx) {
    __shared__ __align__(16) unsigned char smem[BN * 256];   // 16KB swizzled bf16 A-tile
    __shared__ int seg[BN];

    const int t    = threadIdx.x;
    const int lane = t & 63;
    const int wv   = t >> 6;
    const int l15  = lane & 15;
    const int lhi  = lane >> 4;
    const long n0  = (long)blockIdx.x * BN;

    // dtype probe: int64 little-endian => odd words (high words) are 0
    const bool is64 = (batch[NTOT - 1] == 0);
    if (t < BN) {
        long idx = n0 + t;
        seg[t] = batch[is64 ? 2 * idx : idx];
    }

    // stage x[64][128] f32 -> bf16 A-tile in LDS, XOR-swizzled
    #pragma unroll
    for (int i = 0; i < 8; ++i) {
        int idx = i * 256 + t;
        int row = idx >> 5;            // 32 float4-chunks per row
        int c4  = idx & 31;
        const float4 xv = *(const float4*)(x + (n0 + row) * HDIM + c4 * 4);
        u32x2 p;
        p.x = pk_bf16(xv.x, xv.y);
        p.y = pk_bf16(xv.z, xv.w);
        int boff = row * 256 + ((c4 * 8) ^ ((row & 7) << 4));
        *(u32x2*)(smem + boff) = p;
    }
    __syncthreads();

    // C-init = bias (C = A*B + C): value (row, col) -> acc[mf][nf][r], col = wv*64+nf*16+l15
    f32x4 acc[4][4];
    #pragma unroll
    for (int nf = 0; nf < 4; ++nf) {
        float bb = b1[wv * 64 + nf * 16 + l15];
        #pragma unroll
        for (int mf = 0; mf < 4; ++mf)
            acc[mf][nf] = (f32x4){bb, bb, bb, bb};
    }

    // K = 128 in 4 steps of 32; wave wv owns output cols [wv*64, wv*64+64)
    #pragma unroll
    for (int ks = 0; ks < 4; ++ks) {
        const int k0 = ks * 32 + lhi * 8;
        bf16x8 bfrag[4];
        #pragma unroll
        for (int nf = 0; nf < 4; ++nf) {
            int n = wv * 64 + nf * 16 + l15;
            bfrag[nf] = *(const bf16x8*)(W1b + n * HDIM + k0);
        }
        bf16x8 afrag[4];
        #pragma unroll
        for (int mf = 0; mf < 4; ++mf) {
            int m = mf * 16 + l15;
            int boff = m * 256 + ((k0 * 2) ^ ((m & 7) << 4));
            afrag[mf] = *(const bf16x8*)(smem + boff);
        }
        #pragma unroll
        for (int mf = 0; mf < 4; ++mf)
            #pragma unroll
            for (int nf = 0; nf < 4; ++nf)
                acc[mf][nf] = __builtin_amdgcn_mfma_f32_16x16x32_bf16(
                    afrag[mf], bfrag[nf], acc[mf][nf], 0, 0, 0);
    }

    // fast tanh in registers: tanh(s) = 1 - 2/(1 + 2^(s*2*log2e))  (safe at |s| large: inf->+-1)
    #pragma unroll
    for (int mf = 0; mf < 4; ++mf)
        #pragma unroll
        for (int nf = 0; nf < 4; ++nf)
            #pragma unroll
            for (int r = 0; r < 4; ++r) {
                float e = exp2f(acc[mf][nf][r] * 2.885390081777927f);
                acc[mf][nf][r] = 1.0f - 2.0f * __builtin_amdgcn_rcpf(1.0f + e);
            }

    // ---- in-register segmented reduction over the 64 sorted rows ----
    // boundary mask (identical in every wave): bit m set iff seg[m] != seg[m-1]
    unsigned long long bmask;
    {
        int s_here = seg[lane];
        int s_prev = (lane > 0) ? seg[lane - 1] : s_here;
        bmask = __ballot(s_here != s_prev);
    }

    int start = 0;
    unsigned long long rem = bmask;
    for (;;) {
        const int end = rem ? (int)__builtin_ctzll(rem) : BN;
        const int sid = seg[start];
        float p0 = 0.f, p1 = 0.f, p2 = 0.f, p3 = 0.f;
        #pragma unroll
        for (int mf = 0; mf < 4; ++mf)
            #pragma unroll
            for (int r = 0; r < 4; ++r) {
                int row = mf * 16 + lhi * 4 + r;
                float w = ((unsigned)(row - start) < (unsigned)(end - start)) ? 1.0f : 0.0f;
                p0 = fmaf(w, acc[mf][0][r], p0);
                p1 = fmaf(w, acc[mf][1][r], p1);
                p2 = fmaf(w, acc[mf][2][r], p2);
                p3 = fmaf(w, acc[mf][3][r], p3);
            }
        // reduce over lhi (lanes l15 + 16*lhi)
        p0 += __shfl_xor(p0, 16); p0 += __shfl_xor(p0, 32);
        p1 += __shfl_xor(p1, 16); p1 += __shfl_xor(p1, 32);
        p2 += __shfl_xor(p2, 16); p2 += __shfl_xor(p2, 32);
        p3 += __shfl_xor(p3, 16); p3 += __shfl_xor(p3, 32);
        if (lhi == 0) {
            float* base = sumx + (long)sid * ODIM + wv * 64 + l15;
            atomicAdd(base +  0, p0);
            atomicAdd(base + 16, p1);
            atomicAdd(base + 32, p2);
            atomicAdd(base + 48, p3);
        }
        if (rem == 0) break;
        start = end;
        rem &= rem - 1;
    }
}

// y[g][h] = b2[h] + sum_o sumx[g][o] * W2[h][o]   (fp32, 268 MFLOP)
__global__ __launch_bounds__(256)
void stage2(const float* __restrict__ sumx, const float* __restrict__ W2,
            const float* __restrict__ b2, float* __restrict__ y) {
    __shared__ float sx[16 * 256];
    const int t = threadIdx.x;
    const long g0 = (long)blockIdx.x * 16;
    #pragma unroll
    for (int i = 0; i < 16; ++i)
        sx[i * 256 + t] = sumx[(g0 + i) * 256 + t];
    __syncthreads();
    const int h = t & 127;
    const int gl0 = (t >> 7) * 8;
    float acc[8] = {0, 0, 0, 0, 0, 0, 0, 0};
    const float* w = W2 + h * 256;
    for (int o4 = 0; o4 < 64; ++o4) {
        float4 wvv = *(const float4*)(w + o4 * 4);
        #pragma unroll
        for (int gl = 0; gl < 8; ++gl) {
            const float* sr = &sx[(gl0 + gl) * 256 + o4 * 4];
            acc[gl] += sr[0] * wvv.x + sr[1] * wvv.y + sr[2] * wvv.z + sr[3] * wvv.w;
        }
    }
    float bb = b2[h];
    #pragma unroll
    for (int gl = 0; gl < 8; ++gl)
        y[(g0 + gl0 + gl) * 128 + h] = acc[gl] + bb;
}

extern "C" void kernel_launch(void* const* d_in, const int* in_sizes, int n_in,
                              void* d_out, int out_size, void* d_ws, size_t ws_size,
                              hipStream_t stream) {
    const float* x   = (const float*)d_in[0];
    const int* batch = (const int*)d_in[1];
    const float* W1  = (const float*)d_in[2];
    const float* b1  = (const float*)d_in[3];
    const float* W2  = (const float*)d_in[4];
    const float* b2  = (const float*)d_in[5];
    float* y = (float*)d_out;

    float* sumx = (float*)d_ws;                                                   // 4 MB
    unsigned short* W1b = (unsigned short*)((char*)d_ws + (size_t)NSEG * ODIM * 4); // 64 KB

    (void)hipMemsetAsync(sumx, 0, (size_t)NSEG * ODIM * sizeof(float), stream);
    convert_w1<<<dim3((ODIM * HDIM / 2) / 256), dim3(256), 0, stream>>>(W1, (unsigned int*)W1b);
    stage1<<<dim3(NTOT / BN), dim3(256), 0, stream>>>(x, batch, W1b, b1, sumx);
    stage2<<<dim3(NSEG / 16), dim3(256), 0, stream>>>(sumx, W2, b2, y);
}